// Round 3
// baseline (1349.642 us; speedup 1.0000x reference)
//
#include <hip/hip_runtime.h>

// EdgeConv: B=32, N=2048, D=16, PCD=2, K_NN=16, FILTERS=64
// out[b,n,0:64]  = max over 17 conv rows (centre + 16 edges) of edges@W + b
//                = max(y_n, max_k y_{nn_k} - y_n) + b   where y = x@W (linearity)
// out[b,n,64:80] = x[b,n,:]
//
// KNN distance arithmetic must REPLICATE the np reference's fp32 rounding
// (being more accurate loses: identical absmax across fp32-noFMA and fp64
// rounds proved the ref itself flips a 16/17 boundary vs ground truth).
// This round: BLAS/XLA-style contracted dot: dot = fma(y_n,y_m, x_n*x_m);
// sq plain mul+add; dist = (sq_n + sq_m) - 2*dot with no final FMA.

#define B_  32
#define N_  2048
#define D_  16
#define F_  64
#define K_  16
#define OUTD (F_ + D_)   // 80

// ---------------- K1: Y = X * W  (bias folded into pool kernel) -------------
__global__ __launch_bounds__(256) void proj_kernel(const float* __restrict__ x,
                                                   const float* __restrict__ W,
                                                   float* __restrict__ Y) {
    __shared__ float Ws[D_ * F_];     // 4 KB
    __shared__ float xs[4][D_];
    const int t = threadIdx.x;
    for (int i = t; i < D_ * F_; i += 256) Ws[i] = W[i];
    const int p0 = blockIdx.x * 4;
    if (t < 4 * D_) {
        int pw = t / D_, d = t % D_;
        xs[pw][d] = x[(size_t)(p0 + pw) * D_ + d];
    }
    __syncthreads();
    const int w = t >> 6, f = t & 63;
    float acc = 0.f;
#pragma unroll
    for (int d = 0; d < D_; d++) acc = fmaf(xs[w][d], Ws[d * F_ + f], acc);
    Y[(size_t)(p0 + w) * F_ + f] = acc;
}

// ---------------- K2: exact 16-NN per point, fp32 FMA-dot distances ---------
// sq[m]  = fl(fl(x*x) + fl(y*y))                 (no FMA)
// dot    = fma(y_n, y_m, fl(x_n*x_m))            (BLAS k-loop contraction)
// dist   = fl(fl(sq_n + sq_m) - fl(2*dot))       (no final FMA)
// Tie semantics (lower index wins) preserved by ascending scan with strict
// d < worst replacement and lexicographic-(d, idx) worst selection.
__global__ __launch_bounds__(256) void knn_kernel(const float* __restrict__ x,
                                                  int* __restrict__ idx) {
    __shared__ float2 pts[N_];        // 16 KB
    __shared__ float  sqs[N_];        // 8 KB
    const int b = blockIdx.x >> 3;          // 8 blocks per batch
    const int qbase = (blockIdx.x & 7) * 256;
    const int t = threadIdx.x;
    const float* xb = x + (size_t)b * N_ * D_;
    for (int m = t; m < N_; m += 256) {
        float2 p = make_float2(xb[m * D_ + 0], xb[m * D_ + 1]);
        pts[m] = p;
        sqs[m] = __fadd_rn(__fmul_rn(p.x, p.x), __fmul_rn(p.y, p.y));
    }
    __syncthreads();

    const int q = qbase + t;
    const float2 qp = pts[q];
    const float sqn = sqs[q];

    float bd[K_];
    int   bi[K_];
#pragma unroll
    for (int k = 0; k < K_; k++) {
        float2 p = pts[k];
        float dot = __fmaf_rn(qp.y, p.y, __fmul_rn(qp.x, p.x));
        bd[k] = __fsub_rn(__fadd_rn(sqn, sqs[k]), __fmul_rn(2.f, dot));
        bi[k] = k;
    }

    float wd; int wslot;
    {
        wd = bd[0]; int wi = bi[0]; wslot = 0;
#pragma unroll
        for (int j = 1; j < K_; j++) {
            bool g = (bd[j] > wd) || (bd[j] == wd && bi[j] > wi);
            if (g) { wd = bd[j]; wi = bi[j]; wslot = j; }
        }
    }

    for (int m = K_; m < N_; m++) {
        float2 p = pts[m];
        float dot = __fmaf_rn(qp.y, p.y, __fmul_rn(qp.x, p.x));
        float d = __fsub_rn(__fadd_rn(sqn, sqs[m]), __fmul_rn(2.f, dot));
        if (d < wd) {   // d==wd keeps incumbent (lower index) -> top_k semantics
#pragma unroll
            for (int j = 0; j < K_; j++)
                if (j == wslot) { bd[j] = d; bi[j] = m; }
            wd = bd[0]; int wi = bi[0]; wslot = 0;
#pragma unroll
            for (int j = 1; j < K_; j++) {
                bool g = (bd[j] > wd) || (bd[j] == wd && bi[j] > wi);
                if (g) { wd = bd[j]; wi = bi[j]; wslot = j; }
            }
        }
    }

    int* op = idx + ((size_t)b * N_ + q) * K_;
#pragma unroll
    for (int k = 0; k < K_; k++) op[k] = bi[k];
}

// ---------------- K3: gather-max over neighbors + epilogue ------------------
__global__ __launch_bounds__(256) void pool_kernel(const float* __restrict__ x,
                                                   const float* __restrict__ bias,
                                                   const float* __restrict__ Y,
                                                   const int* __restrict__ idx,
                                                   float* __restrict__ out) {
    const int t = threadIdx.x;
    const int w = t >> 6, f = t & 63;
    const int p = blockIdx.x * 4 + w;       // global point id
    const int b = p >> 11;                  // p / N_
    const size_t pb = (size_t)p;

    const float yn = Y[pb * F_ + f];
    const int* ip = idx + pb * K_;
    float M = -INFINITY;
#pragma unroll
    for (int k = 0; k < K_; k++) {
        int m = ip[k];
        float ym = Y[((size_t)b * N_ + m) * F_ + f];
        M = fmaxf(M, ym);
    }
    float pooled = fmaxf(yn, M - yn) + bias[f];
    out[pb * OUTD + f] = pooled;
    if (f < D_) out[pb * OUTD + F_ + f] = x[pb * D_ + f];
}

extern "C" void kernel_launch(void* const* d_in, const int* in_sizes, int n_in,
                              void* d_out, int out_size, void* d_ws, size_t ws_size,
                              hipStream_t stream) {
    const float* x    = (const float*)d_in[0];
    const float* W    = (const float*)d_in[1];
    const float* bias = (const float*)d_in[2];
    float* out = (float*)d_out;

    float* Y  = (float*)d_ws;                                        // 16.78 MB
    int*  idx = (int*)((char*)d_ws + (size_t)B_ * N_ * F_ * 4);      // +4.19 MB

    proj_kernel<<<B_ * N_ / 4, 256, 0, stream>>>(x, W, Y);
    knn_kernel <<<B_ * (N_ / 256), 256, 0, stream>>>(x, idx);
    pool_kernel<<<B_ * N_ / 4, 256, 0, stream>>>(x, bias, Y, idx, out);
}